// Round 1
// baseline (577.717 us; speedup 1.0000x reference)
//
#include <hip/hip_runtime.h>

// Depthwise directional conv: B=32, C=160 (=32 central + 4x32 directional), H=W=128.
// Memory-bound (671 MB min traffic -> ~107 us floor at 6.3 TB/s).
// One block = 8 rows x 128 cols of one (b,c) plane; 256 thr, each does one float4.

#define Hc 128
#define Wc 128
#define Cc 160

__device__ __forceinline__ float ldx(const float* __restrict__ row, int w) {
    return ((unsigned)w < (unsigned)Wc) ? row[w] : 0.0f;
}

__global__ __launch_bounds__(256) void ddw_kernel(
    const float* __restrict__ x, const float* __restrict__ cen,
    const float* __restrict__ dir, float* __restrict__ out)
{
    const int plane = blockIdx.y;            // b*C + c
    const int c = plane % Cc;
    const float* __restrict__ xp = x + (size_t)plane * (Hc * Wc);
    float* __restrict__ op = out + (size_t)plane * (Hc * Wc);

    const int tid = threadIdx.x;
    const int r  = blockIdx.x * 8 + (tid >> 5);   // row 0..127
    const int w0 = (tid & 31) << 2;               // col 0,4,...,124 (16B aligned)

    float a0 = 0.f, a1 = 0.f, a2 = 0.f, a3 = 0.f;
    const int grp = c >> 5;   // 0 cen, 1 horiz, 2 vert, 3 diag, 4 adiag (block-uniform)

    if (grp == 0) {
        // 3x3 centered in 5x5 == 3x3 conv, pad 1
        const float* cw = cen + c * 9;
        float k[9];
        #pragma unroll
        for (int i = 0; i < 9; i++) k[i] = cw[i];
        #pragma unroll
        for (int dh = -1; dh <= 1; dh++) {
            int hh = r + dh;
            if ((unsigned)hh >= (unsigned)Hc) continue;
            const float* row = xp + hh * Wc;
            float4 m = *(const float4*)(row + w0);
            float v0 = ldx(row, w0 - 1);
            float v5 = ldx(row, w0 + 4);
            const float* kk = k + (dh + 1) * 3;
            a0 += kk[0] * v0  + kk[1] * m.x + kk[2] * m.y;
            a1 += kk[0] * m.x + kk[1] * m.y + kk[2] * m.z;
            a2 += kk[0] * m.y + kk[1] * m.z + kk[2] * m.w;
            a3 += kk[0] * m.z + kk[1] * m.w + kk[2] * v5;
        }
    } else {
        const float* dw = dir + (c & 31) * 5;
        float d[5];
        #pragma unroll
        for (int i = 0; i < 5; i++) d[i] = dw[i];

        if (grp == 1) {
            // horizontal: out[w] = sum_t x[h, w-2+t] * d[t]
            const float* row = xp + r * Wc;
            float4 m = *(const float4*)(row + w0);
            float v[8];
            v[0] = ldx(row, w0 - 2); v[1] = ldx(row, w0 - 1);
            v[2] = m.x; v[3] = m.y; v[4] = m.z; v[5] = m.w;
            v[6] = ldx(row, w0 + 4); v[7] = ldx(row, w0 + 5);
            #pragma unroll
            for (int t = 0; t < 5; t++) {
                a0 += d[t] * v[t];
                a1 += d[t] * v[t + 1];
                a2 += d[t] * v[t + 2];
                a3 += d[t] * v[t + 3];
            }
        } else if (grp == 2) {
            // vertical: out = sum_t x[h-2+t, w] * d[t]
            #pragma unroll
            for (int t = 0; t < 5; t++) {
                int hh = r + t - 2;
                if ((unsigned)hh >= (unsigned)Hc) continue;
                float4 m = *(const float4*)(xp + hh * Wc + w0);
                a0 += d[t] * m.x; a1 += d[t] * m.y;
                a2 += d[t] * m.z; a3 += d[t] * m.w;
            }
        } else if (grp == 3) {
            // main diagonal: out = sum_t x[h-2+t, w-2+t] * d[t]
            #pragma unroll
            for (int t = 0; t < 5; t++) {
                int hh = r + t - 2;
                if ((unsigned)hh >= (unsigned)Hc) continue;
                const float* row = xp + hh * Wc;
                int wb = w0 + t - 2;
                a0 += d[t] * ldx(row, wb);
                a1 += d[t] * ldx(row, wb + 1);
                a2 += d[t] * ldx(row, wb + 2);
                a3 += d[t] * ldx(row, wb + 3);
            }
        } else {
            // anti-diagonal: out = sum_t x[h-2+t, w+2-t] * d[t]
            #pragma unroll
            for (int t = 0; t < 5; t++) {
                int hh = r + t - 2;
                if ((unsigned)hh >= (unsigned)Hc) continue;
                const float* row = xp + hh * Wc;
                int wb = w0 + 2 - t;
                a0 += d[t] * ldx(row, wb);
                a1 += d[t] * ldx(row, wb + 1);
                a2 += d[t] * ldx(row, wb + 2);
                a3 += d[t] * ldx(row, wb + 3);
            }
        }
    }

    float4 res = make_float4(a0, a1, a2, a3);
    *(float4*)(op + r * Wc + w0) = res;
}

extern "C" void kernel_launch(void* const* d_in, const int* in_sizes, int n_in,
                              void* d_out, int out_size, void* d_ws, size_t ws_size,
                              hipStream_t stream) {
    const float* x   = (const float*)d_in[0];   // [32,160,128,128]
    const float* cen = (const float*)d_in[1];   // [32,3,3]
    const float* dir = (const float*)d_in[2];   // [32,5]
    float* out = (float*)d_out;                 // [32,160,128,128]

    dim3 grid(Hc / 8, 32 * Cc);                 // (16, 5120)
    ddw_kernel<<<grid, 256, 0, stream>>>(x, cen, dir, out);
}

// Round 2
// 527.327 us; speedup vs baseline: 1.0956x; 1.0956x over previous
//
#include <hip/hip_runtime.h>

// Depthwise directional conv: B=32, C=160 (=32 central 3x3 + 4x32 directional 5-tap), H=W=128.
// Memory-bound problem: ~840 MB HBM round trip -> ~130 us floor at 6.4 TB/s.
// R1 lesson: bounds-checked scalar global loads serialize on memory latency (578 us).
// R2: LDS-staged tile. Block = 8 rows x 128 cols of one (b,c) plane, 256 threads.
// LDS tile 12 rows x 136 floats (±2 row halo, 4-col halo incl. alignment pad),
// zero-filled halo -> no bounds checks in compute; batched float4 global loads.

#define Hc 128
#define Wc 128
#define Cc 160
#define TR 8       // output rows per block
#define LW 136     // LDS row stride in floats; col w maps to l = w + 4 (keeps float4 writes 16B-aligned)

__global__ __launch_bounds__(256) void ddw_kernel(
    const float* __restrict__ x, const float* __restrict__ cen,
    const float* __restrict__ dir, float* __restrict__ out)
{
    __shared__ float t[(TR + 4) * LW];

    const int plane = blockIdx.y;            // b*C + c
    const int c = plane % Cc;
    const float* __restrict__ xp = x + (size_t)plane * (Hc * Wc);
    float* __restrict__ op = out + (size_t)plane * (Hc * Wc);

    const int tid = threadIdx.x;
    const int r0 = blockIdx.x * TR;

    // Zero the column halo: l in {2,3,132,133} for all 12 rows (always outside plane).
    if (tid < 48) {
        int row = tid >> 2, j = tid & 3;
        int l = (j < 2) ? (2 + j) : (130 + j);   // 2,3,132,133
        t[row * LW + l] = 0.0f;
    }
    // Main region: 12 rows x 32 float4 = 384 slots; coalesced, zero-fill OOB rows.
    #pragma unroll
    for (int it = 0; it < 2; ++it) {
        int s = tid + it * 256;
        if (s < 12 * 32) {
            int row = s >> 5, q = s & 31;
            int gr = r0 - 2 + row;
            float4 v = make_float4(0.f, 0.f, 0.f, 0.f);
            if ((unsigned)gr < (unsigned)Hc)
                v = *(const float4*)(xp + gr * Wc + (q << 2));
            *(float4*)&t[row * LW + 4 + (q << 2)] = v;
        }
    }
    __syncthreads();

    const int rl = tid >> 5;                 // 0..7 local row
    const int w0 = (tid & 31) << 2;          // 0..124
    const float* __restrict__ trow = &t[(rl + 2) * LW + (w0 + 4)];  // center of this thread's 4 outputs

    float a0 = 0.f, a1 = 0.f, a2 = 0.f, a3 = 0.f;
    const int grp = c >> 5;                  // block-uniform

    if (grp == 0) {
        // 3x3 centered in 5x5 => offsets -1..+1
        const float* cw = cen + c * 9;
        #pragma unroll
        for (int dh = 0; dh < 3; dh++) {
            const float* rr = trow + (dh - 1) * LW;
            float v0 = rr[-1], v1 = rr[0], v2 = rr[1], v3 = rr[2], v4 = rr[3], v5 = rr[4];
            float k0 = cw[dh * 3 + 0], k1 = cw[dh * 3 + 1], k2 = cw[dh * 3 + 2];
            a0 += k0 * v0 + k1 * v1 + k2 * v2;
            a1 += k0 * v1 + k1 * v2 + k2 * v3;
            a2 += k0 * v2 + k1 * v3 + k2 * v4;
            a3 += k0 * v3 + k1 * v4 + k2 * v5;
        }
    } else {
        const float* dw = dir + (c & 31) * 5;
        float d[5];
        #pragma unroll
        for (int i = 0; i < 5; i++) d[i] = dw[i];

        if (grp == 1) {
            // horizontal: out[w+i] = sum_t x[h, w+i+t-2] d[t]
            float v[8];
            #pragma unroll
            for (int i = 0; i < 8; i++) v[i] = trow[i - 2];
            #pragma unroll
            for (int tt = 0; tt < 5; tt++) {
                a0 += d[tt] * v[tt];
                a1 += d[tt] * v[tt + 1];
                a2 += d[tt] * v[tt + 2];
                a3 += d[tt] * v[tt + 3];
            }
        } else if (grp == 2) {
            // vertical: out[w+i] = sum_t x[h+t-2, w+i] d[t]  (aligned float4 LDS reads)
            #pragma unroll
            for (int tt = 0; tt < 5; tt++) {
                float4 m = *(const float4*)(trow + (tt - 2) * LW);
                a0 += d[tt] * m.x; a1 += d[tt] * m.y;
                a2 += d[tt] * m.z; a3 += d[tt] * m.w;
            }
        } else if (grp == 3) {
            // main diagonal: out[w+i] = sum_t x[h+t-2, w+i+t-2] d[t]
            #pragma unroll
            for (int tt = 0; tt < 5; tt++) {
                const float* rr = trow + (tt - 2) * LW + (tt - 2);
                a0 += d[tt] * rr[0];
                a1 += d[tt] * rr[1];
                a2 += d[tt] * rr[2];
                a3 += d[tt] * rr[3];
            }
        } else {
            // anti-diagonal: out[w+i] = sum_t x[h+t-2, w+i+2-t] d[t]
            #pragma unroll
            for (int tt = 0; tt < 5; tt++) {
                const float* rr = trow + (tt - 2) * LW + (2 - tt);
                a0 += d[tt] * rr[0];
                a1 += d[tt] * rr[1];
                a2 += d[tt] * rr[2];
                a3 += d[tt] * rr[3];
            }
        }
    }

    *(float4*)(op + (r0 + rl) * Wc + w0) = make_float4(a0, a1, a2, a3);
}

extern "C" void kernel_launch(void* const* d_in, const int* in_sizes, int n_in,
                              void* d_out, int out_size, void* d_ws, size_t ws_size,
                              hipStream_t stream) {
    const float* x   = (const float*)d_in[0];   // [32,160,128,128]
    const float* cen = (const float*)d_in[1];   // [32,3,3]
    const float* dir = (const float*)d_in[2];   // [32,5]
    float* out = (float*)d_out;                 // [32,160,128,128]

    dim3 grid(Hc / TR, 32 * Cc);                // (16, 5120)
    ddw_kernel<<<grid, 256, 0, stream>>>(x, cen, dir, out);
}